// Round 15
// baseline (260.550 us; speedup 1.0000x reference)
//
#include <hip/hip_runtime.h>
#include <hip/hip_cooperative_groups.h>
#include <stdint.h>

namespace cg = cooperative_groups;

// x: [16,3,64,64,64] f32; w: [16,3,3,3,3] f32; conv valid -> 62^3.
// out[b,c] = gw[c]*(mean_sp(a)-mu[b,g])*rsqrt(var[b,g]+eps)+gb[c],
// a = hardswish(conv+bias) -> only per-channel sums S1 / per-group sum-sq S2
// needed. Conv = implicit GEMM on bf16 MFMA (per row: M=16 w x N=16 cout,
// K=27->32; kw as 3 column-shifted reads of one per-wave im2col).
// R11 evidence: conv 51us (VALUBusy 47, MfmaUtil 18) but total 128us ->
// ~77us = 3 dispatch overheads (~15-20us each) + prep + finalize.
// R12: ONE cooperative kernel (guide-sanctioned): 1024 blocks = 4/CU
// co-resident; each block = fixed (b, hp-group), loops 16 consecutive dp
// tiles (B-frags computed once/block, epilogue reduction once/block, L1
// locality on x rows); grid.sync(); 16 blocks finalize.
constexpr int OD = 62;
constexpr float EPSV = 1e-5f;

typedef __attribute__((ext_vector_type(8))) short bf16x8;  // 8 bf16 = 4 VGPR
typedef __attribute__((ext_vector_type(4))) float f32x4;

__device__ __forceinline__ uint32_t bf16rne(float f) {
    uint32_t u = __float_as_uint(f);
    return (u + 0x7FFFu + ((u >> 16) & 1u)) >> 16;
}
__device__ __forceinline__ float bf16tof(uint32_t h) { return __uint_as_float(h << 16); }
__device__ __forceinline__ uint32_t cvtpk(float a, float b) {   // lo=bf16(a), hi=bf16(b), RNE
    uint32_t r;
    asm("v_cvt_pk_bf16_f32 %0, %1, %2" : "=v"(r) : "v"(a), "v"(b));
    return r;
}

union U8 { uint32_t u[4]; bf16x8 v; };

// part layout: part[(b*20 + s)*64 + sub], sub = block-within-batch 0..63.
__global__ __launch_bounds__(256, 4)
void conv_gn_coop(const float* __restrict__ x, const float* __restrict__ wgt,
                  const float* __restrict__ cbias, const float* __restrict__ gw,
                  const float* __restrict__ gb, float* __restrict__ part,
                  float* __restrict__ out)
{
    // im2col per wave: 4 g-chunks x 66 columns x 4 pair-dwords (16B/column).
    __shared__ __align__(16) uint32_t im2[4224];
    __shared__ float red[20];
    const int tid = threadIdx.x, wq = tid >> 6, l = tid & 63;
    const int lm = l & 15, lg = l >> 4;
    if (tid < 20) red[tid] = 0.f;
    __syncthreads();

    const int beta = blockIdx.x;       // 0..1023
    const int b    = beta >> 6;        // batch
    const int sub  = beta & 63;        // 4 dp-ranges x 16 hp-groups
    const int hg   = sub & 15;
    const int dp0  = (sub >> 4) * 16;  // 0,16,32,48
    const int hp   = hg * 4 + wq;      // fixed row per wave; 62,63 idle

    float s1 = 0.f, s2 = 0.f;

    if (hp < OD) {
        // ---- B fragments: computed ONCE per block (amortized over 16 dp) ----
        bf16x8 Bhi[3], Blo[3];
#pragma unroll
        for (int kw = 0; kw < 3; ++kw) {
            U8 h8, l8;
#pragma unroll
            for (int p = 0; p < 4; ++p) {
                uint32_t hv[2], lv[2];
#pragma unroll
                for (int e = 0; e < 2; ++e) {
                    const int kp = lg * 8 + p * 2 + e;
                    const float wv = (kp < 27) ? wgt[lm * 81 + kp * 3 + kw] : 0.f;
                    hv[e] = bf16rne(wv);
                    lv[e] = bf16rne(wv - bf16tof(hv[e]));
                }
                h8.u[p] = hv[0] | (hv[1] << 16);
                l8.u[p] = lv[0] | (lv[1] << 16);
            }
            Bhi[kw] = h8.v; Blo[kw] = l8.v;
        }
        const float bz = cbias[lm];

        // zero pad columns 64,65 once (never overwritten afterwards)
        if (l < 2) {
#pragma unroll
            for (int g = 0; g < 4; ++g)
                *reinterpret_cast<uint4*>(&im2[(wq * 4 + g) * 264 + (64 + l) * 4]) =
                    make_uint4(0u, 0u, 0u, 0u);
        }

        const float* xrow = x + (size_t)b * 786432 + hp * 64 + l;  // + dp*4096 per tile

#pragma unroll 2
        for (int j = 0; j < 16; ++j) {
            const int dp = dp0 + j;
            if (dp >= OD) break;                    // only dp0=48 range trims
            const float* base2 = xrow + dp * 4096;

            // ---- build im2col (lane l = w column) ----
#pragma unroll
            for (int g = 0; g < 4; ++g) {
                float v[8];
#pragma unroll
                for (int jj = 0; jj < 8; ++jj) {
                    const int kp = g * 8 + jj;      // k' = ci*9+kd*3+kh
                    if (kp < 27) {
                        const int ci = kp / 9, kd = (kp % 9) / 3, kh = kp % 3;
                        v[jj] = base2[ci * 262144 + kd * 4096 + kh * 64];
                    } else v[jj] = 0.f;
                }
                *reinterpret_cast<uint4*>(&im2[(wq * 4 + g) * 264 + l * 4]) =
                    make_uint4(cvtpk(v[0], v[1]), cvtpk(v[2], v[3]),
                               cvtpk(v[4], v[5]), cvtpk(v[6], v[7]));
            }
            // wave-private region; same-wave DS ops are in-order (WAR safe).

            // ---- MFMA: 4 M-tiles x 3 kw-shifts x (hi,lo) ----
            f32x4 acc[4] = {{0,0,0,0},{0,0,0,0},{0,0,0,0},{0,0,0,0}};
            const uint32_t* abase = &im2[wq * 1056 + lg * 264];
#pragma unroll
            for (int t = 0; t < 4; ++t) {
#pragma unroll
                for (int kw = 0; kw < 3; ++kw) {
                    const bf16x8 a =
                        *reinterpret_cast<const bf16x8*>(abase + (t * 16 + lm + kw) * 4);
                    acc[t] = __builtin_amdgcn_mfma_f32_16x16x32_bf16(a, Bhi[kw], acc[t], 0, 0, 0);
                    acc[t] = __builtin_amdgcn_mfma_f32_16x16x32_bf16(a, Blo[kw], acc[t], 0, 0, 0);
                }
            }

            // ---- hardswish + masked accumulate (C: col=lane&15, row=lg*4+reg) ----
#pragma unroll
            for (int t = 0; t < 4; ++t) {
#pragma unroll
                for (int rr = 0; rr < 4; ++rr) {
                    const float z = acc[t][rr] + bz;
                    const float r6 = fminf(fmaxf(z + 3.f, 0.f), 6.f);
                    const float a = z * r6 * (1.f / 6.f);
                    const bool ok = (t < 3) | ((lg * 4 + rr) < 14);   // w=48+m<62
                    s1 += ok ? a : 0.f;
                    s2 += ok ? a * a : 0.f;
                }
            }
        }

        // ---- per-block reduction (once, not per tile) ----
        s1 += __shfl_xor(s1, 16); s1 += __shfl_xor(s1, 32);
        s2 += __shfl_xor(s2, 16); s2 += __shfl_xor(s2, 32);
        float s2g = s2;
        s2g += __shfl_xor(s2g, 1); s2g += __shfl_xor(s2g, 2);
        if (l < 16) {
            atomicAdd(&red[l], s1);
            if ((l & 3) == 0) atomicAdd(&red[16 + (l >> 2)], s2g);
        }
    }
    __syncthreads();
    if (tid < 20) part[(b * 20 + tid) * 64 + sub] = red[tid];

    cg::this_grid().sync();

    // ---- finalize: 16 blocks, one per batch ----
    if (beta < 16) {
        const int bb = beta;
        if (tid < 20) {
            const float* p = part + (bb * 20 + tid) * 64;
            float a = 0.f;
#pragma unroll
            for (int k = 0; k < 64; ++k) a += p[k];
            red[tid] = a;                    // reuse red as totals
        }
        __syncthreads();
        if (tid < 16) {
            const float invN  = 1.0f / 238328.0f;
            const float invGN = 1.0f / (4.0f * 238328.0f);
            const int g = tid >> 2;
            const float mu  = (red[g * 4] + red[g * 4 + 1] +
                               red[g * 4 + 2] + red[g * 4 + 3]) * invGN;
            const float var = red[16 + g] * invGN - mu * mu;
            out[bb * 16 + tid] = gw[tid] * (red[tid] * invN - mu) * rsqrtf(var + EPSV) + gb[tid];
        }
    }
}

extern "C" void kernel_launch(void* const* d_in, const int* in_sizes, int n_in,
                              void* d_out, int out_size, void* d_ws, size_t ws_size,
                              hipStream_t stream) {
    const float* x  = (const float*)d_in[0];
    const float* w  = (const float*)d_in[1];
    const float* cb = (const float*)d_in[2];
    const float* gw = (const float*)d_in[3];
    const float* gb = (const float*)d_in[4];
    float* out  = (float*)d_out;
    float* part = (float*)d_ws;                 // 16*20*64 f32 = 80 KB

    void* args[] = {(void*)&x, (void*)&w, (void*)&cb, (void*)&gw, (void*)&gb,
                    (void*)&part, (void*)&out};
    hipLaunchCooperativeKernel((const void*)conv_gn_coop, dim3(1024), dim3(256),
                               args, 0, stream);
}